// Round 2
// baseline (584.814 us; speedup 1.0000x reference)
//
#include <hip/hip_runtime.h>
#include <hip/hip_cooperative_groups.h>
#include <math.h>

namespace cg = cooperative_groups;

#define NB 16
#define IMH 288
#define IMW 384
#define NPIX (IMH*IMW)
#define NBLK 512
#define BPB (NBLK/NB)   // 32 blocks per batch
#define TPB 256
#define NITER 5

// ws doubles layout: R[16][9] | t[16][3] | acc[16][27] ; then ints: cnt[16][NITER]
#define R_OFF 0
#define T_OFF (NB*9)
#define ACC_OFF (NB*12)
#define WS_DOUBLES (NB*12 + NB*27)

__device__ void solve_batch(double* ws, int b) {
    double* acc = ws + ACC_OFF + b * 27;
    double A[6][6], rhs[6];
    int k = 0;
    for (int f = 0; f < 6; f++)
        for (int g = f; g < 6; g++) {
            A[f][g] = acc[k]; A[g][f] = acc[k]; k++;
        }
    for (int f = 0; f < 6; f++) rhs[f] = -acc[21 + f];

    double tr = A[0][0] + A[1][1] + A[2][2] + A[3][3] + A[4][4] + A[5][5];
    double damp = 1e-4 * tr / 6.0 + 1e-6;
    for (int f = 0; f < 6; f++) A[f][f] += damp;

    double L[6][6];
    for (int i = 0; i < 6; i++)
        for (int j = 0; j <= i; j++) {
            double sum = A[i][j];
            for (int m = 0; m < j; m++) sum -= L[i][m] * L[j][m];
            if (i == j) L[i][j] = sqrt(fmax(sum, 1e-30));
            else        L[i][j] = sum / L[j][j];
        }
    double y[6];
    for (int i = 0; i < 6; i++) {
        double s = rhs[i];
        for (int m = 0; m < i; m++) s -= L[i][m] * y[m];
        y[i] = s / L[i][i];
    }
    double dx[6];
    for (int i = 5; i >= 0; i--) {
        double s = y[i];
        for (int m = i + 1; m < 6; m++) s -= L[m][i] * dx[m];
        dx[i] = s / L[i][i];
    }

    double* t = ws + T_OFF + b * 3;
    t[0] += dx[0]; t[1] += dx[1]; t[2] += dx[2];

    double wx = dx[3], wy = dx[4], wz = dx[5];
    double th = sqrt(wx*wx + wy*wy + wz*wz);
    th = fmax(th, 1e-8);
    double kx = wx/th, ky = wy/th, kz = wz/th;
    double st = sin(th), ct = 1.0 - cos(th);
    double E[9];
    E[0] = 1.0 + ct*(kx*kx - 1.0);
    E[1] = -st*kz + ct*kx*ky;
    E[2] =  st*ky + ct*kx*kz;
    E[3] =  st*kz + ct*ky*kx;
    E[4] = 1.0 + ct*(ky*ky - 1.0);
    E[5] = -st*kx + ct*ky*kz;
    E[6] = -st*ky + ct*kz*kx;
    E[7] =  st*kx + ct*kz*ky;
    E[8] = 1.0 + ct*(kz*kz - 1.0);

    double* R = ws + R_OFF + b * 9;
    double Rn[9];
    for (int i = 0; i < 3; i++)
        for (int j = 0; j < 3; j++)
            Rn[i*3+j] = E[i*3+0]*R[0*3+j] + E[i*3+1]*R[1*3+j] + E[i*3+2]*R[2*3+j];
    for (int i = 0; i < 9; i++) R[i] = Rn[i];

    for (int i = 0; i < 27; i++) acc[i] = 0.0;   // ready for next iteration
}

__global__ __launch_bounds__(TPB, 2) void fused_k(
    const float* __restrict__ x3d, const float* __restrict__ conf,
    const float* __restrict__ Kmat, const float* __restrict__ pose,
    float* __restrict__ out, double* ws)
{
    cg::grid_group grid = cg::this_grid();
    int* cnt = (int*)(ws + WS_DOUBLES);
    const int b = blockIdx.x / BPB;
    const int chunk = blockIdx.x % BPB;

    // --- init (block 0) ---
    if (blockIdx.x == 0) {
        for (int k = threadIdx.x; k < WS_DOUBLES; k += TPB) ws[k] = 0.0;
        for (int k = threadIdx.x; k < NB * NITER; k += TPB) cnt[k] = 0;
        __syncthreads();
        if (threadIdx.x < NB) {
            double* R = ws + R_OFF + threadIdx.x * 9;
            R[0] = 1.0; R[4] = 1.0; R[8] = 1.0;
        }
        __threadfence();
    }
    grid.sync();

    const float fx = Kmat[b*9 + 0];
    const float fy = Kmat[b*9 + 4];
    const float cx = Kmat[b*9 + 2];
    const float cy = Kmat[b*9 + 5];
    const float delta = (float)(0.1 * sqrt(((double)(IMW*IMW - 1) + (double)(IMH*IMH - 1)) / 12.0));

    const float* P  = x3d  + (size_t)b * NPIX * 3;
    const float* Wp = conf + (size_t)b * NPIX;

    __shared__ double lds[TPB / 64][27];
    __shared__ int s_last;

    for (int it = 0; it < NITER; ++it) {
        // read current pose (uniform per block)
        const double* Rd = ws + R_OFF + b * 9;
        const double* td = ws + T_OFF + b * 3;
        float R[9], t[3];
        #pragma unroll
        for (int i = 0; i < 9; i++) R[i] = (float)Rd[i];
        #pragma unroll
        for (int i = 0; i < 3; i++) t[i] = (float)td[i];

        float facc[27];
        #pragma unroll
        for (int i = 0; i < 27; i++) facc[i] = 0.0f;

        for (int n = chunk * TPB + threadIdx.x; n < NPIX; n += BPB * TPB) {
            float px = P[3*n + 0];
            float py = P[3*n + 1];
            float pz = P[3*n + 2];
            float w  = Wp[n];

            float Xx = R[0]*px + R[1]*py + R[2]*pz + t[0];
            float Xy = R[3]*px + R[4]*py + R[5]*pz + t[1];
            float Xz = R[6]*px + R[7]*py + R[8]*pz + t[2];
            float z  = fmaxf(Xz, 0.01f);
            float iz = 1.0f / z;

            int v0 = n / IMW;
            int u0 = n - v0 * IMW;
            float rx = fx * Xx * iz + cx - (float)u0;
            float ry = fy * Xy * iz + cy - (float)v0;

            float wrx = w * rx, wry = w * ry;
            float rn = sqrtf(wrx*wrx + wry*wry);
            float rob2 = fminf(1.0f, delta / fmaxf(rn, 1e-8f));
            float s = w * w * rob2;

            float a  = fx * iz;
            float bb = -fx * Xx * iz * iz;
            float c  = fy * iz;
            float d  = -fy * Xy * iz * iz;

            float j0[6] = { a, 0.0f, bb,  bb*Xy,          a*Xz - bb*Xx, -a*Xy };
            float j1[6] = { 0.0f, c,  d, -c*Xz + d*Xy,   -d*Xx,          c*Xx };

            int k = 0;
            #pragma unroll
            for (int f = 0; f < 6; ++f) {
                #pragma unroll
                for (int g = f; g < 6; ++g) {
                    facc[k] += s * (j0[f]*j0[g] + j1[f]*j1[g]);
                    k++;
                }
            }
            #pragma unroll
            for (int f = 0; f < 6; ++f)
                facc[21 + f] += s * (j0[f]*rx + j1[f]*ry);
        }

        // f64 wave reduction
        int lane = threadIdx.x & 63;
        int wave = threadIdx.x >> 6;
        #pragma unroll
        for (int i = 0; i < 27; i++) {
            double v = (double)facc[i];
            for (int off = 32; off > 0; off >>= 1) v += __shfl_down(v, off, 64);
            if (lane == 0) lds[wave][i] = v;
        }
        __syncthreads();
        if (threadIdx.x < 27) {
            double v = 0.0;
            #pragma unroll
            for (int wv = 0; wv < TPB/64; wv++) v += lds[wv][threadIdx.x];
            atomicAdd(ws + ACC_OFF + b*27 + threadIdx.x, v);
        }
        __threadfence();          // release: acc adds visible before counter bump
        __syncthreads();
        if (threadIdx.x == 0) {
            int old = atomicAdd(&cnt[b*NITER + it], 1);
            s_last = (old == BPB - 1) ? 1 : 0;
        }
        __syncthreads();
        if (s_last && threadIdx.x == 0) {
            __threadfence();      // acquire: see all blocks' acc adds
            solve_batch(ws, b);
            __threadfence();      // release pose update
        }
        __syncthreads();
        grid.sync();              // pose update visible to all blocks
    }

    // --- final loss (block 0) ---
    if (blockIdx.x == 0) {
        int lane = threadIdx.x;
        double rot = 0.0, trans = 0.0;
        if (lane < NB) {
            const float* P0 = pose;
            const float* Pb = pose + lane * 16;
            double R0t[9];
            for (int i = 0; i < 3; i++)
                for (int j = 0; j < 3; j++) R0t[i*3+j] = (double)P0[j*4+i];
            double t0i[3];
            for (int i = 0; i < 3; i++)
                t0i[i] = -(R0t[i*3+0]*P0[0*4+3] + R0t[i*3+1]*P0[1*4+3] + R0t[i*3+2]*P0[2*4+3]);
            double Rg[9], tg[3];
            for (int i = 0; i < 3; i++) {
                for (int j = 0; j < 3; j++)
                    Rg[i*3+j] = R0t[i*3+0]*Pb[0*4+j] + R0t[i*3+1]*Pb[1*4+j] + R0t[i*3+2]*Pb[2*4+j];
                tg[i] = R0t[i*3+0]*Pb[0*4+3] + R0t[i*3+1]*Pb[1*4+3] + R0t[i*3+2]*Pb[2*4+3] + t0i[i];
            }
            const double* Q0  = ws + R_OFF;
            const double* q0t = ws + T_OFF;
            const double* Qb  = ws + R_OFF + lane * 9;
            const double* qbt = ws + T_OFF + lane * 3;
            double Rp0t[9];
            for (int i = 0; i < 3; i++)
                for (int j = 0; j < 3; j++) Rp0t[i*3+j] = Q0[j*3+i];
            double tp0i[3];
            for (int i = 0; i < 3; i++)
                tp0i[i] = -(Rp0t[i*3+0]*q0t[0] + Rp0t[i*3+1]*q0t[1] + Rp0t[i*3+2]*q0t[2]);
            double Rp[9], tp[3];
            for (int i = 0; i < 3; i++) {
                for (int j = 0; j < 3; j++)
                    Rp[i*3+j] = Rp0t[i*3+0]*Qb[0*3+j] + Rp0t[i*3+1]*Qb[1*3+j] + Rp0t[i*3+2]*Qb[2*3+j];
                tp[i] = Rp0t[i*3+0]*qbt[0] + Rp0t[i*3+1]*qbt[1] + Rp0t[i*3+2]*qbt[2] + tp0i[i];
            }
            double trace = 0.0;
            for (int i = 0; i < 3; i++)
                trace += Rp[0*3+i]*Rg[0*3+i] + Rp[1*3+i]*Rg[1*3+i] + Rp[2*3+i]*Rg[2*3+i];
            double cosang = 0.5 * (trace - 1.0);
            double lo = -1.0 + 1e-7, hi = 1.0 - 1e-7;
            cosang = fmin(fmax(cosang, lo), hi);
            rot = acos(cosang);
            double d0 = tp[0]-tg[0], d1 = tp[1]-tg[1], d2 = tp[2]-tg[2];
            trans = sqrt(d0*d0 + d1*d1 + d2*d2);
        }
        if (threadIdx.x < 64) {
            for (int off = 8; off > 0; off >>= 1) {
                rot   += __shfl_down(rot, off, 64);
                trans += __shfl_down(trans, off, 64);
            }
            if (lane == 0) {
                rot /= NB; trans /= NB;
                out[0] = (float)(rot + trans);
                out[1] = (float)rot;
                out[2] = (float)trans;
            }
        }
    }
}

extern "C" void kernel_launch(void* const* d_in, const int* in_sizes, int n_in,
                              void* d_out, int out_size, void* d_ws, size_t ws_size,
                              hipStream_t stream) {
    const float* x3d  = (const float*)d_in[0];
    const float* conf = (const float*)d_in[1];
    const float* Kmat = (const float*)d_in[2];
    const float* pose = (const float*)d_in[3];
    float* out = (float*)d_out;
    double* ws = (double*)d_ws;

    void* args[] = { (void*)&x3d, (void*)&conf, (void*)&Kmat, (void*)&pose,
                     (void*)&out, (void*)&ws };
    hipLaunchCooperativeKernel((const void*)fused_k, dim3(NBLK), dim3(TPB),
                               args, 0, stream);
}

// Round 3
// 376.607 us; speedup vs baseline: 1.5528x; 1.5528x over previous
//
#include <hip/hip_runtime.h>
#include <math.h>

#define NB 16
#define IMH 288
#define IMW 384
#define NPIX (IMH*IMW)
#define BPB 64            // blocks per batch
#define NBLK (NB*BPB)     // 1024
#define TPB 256
#define NITER 5

// ws layout (doubles): R[16][9] | t[16][3] | acc[NITER][16][27]
// then (ints): cnt[NITER*NB] | done
#define R_OFF 0
#define T_OFF (NB*9)
#define ACC_OFF (NB*12)
#define WS_DOUBLES (NB*12 + NITER*NB*27)

__global__ void init_k(double* ws) {
    int i = threadIdx.x;
    for (int k = i; k < WS_DOUBLES; k += TPB) ws[k] = 0.0;
    int* cnt = (int*)(ws + WS_DOUBLES);
    for (int k = i; k < NITER * NB + 1; k += TPB) cnt[k] = 0;
    __syncthreads();
    if (i < NB) {
        double* R = ws + R_OFF + i * 9;
        R[0] = 1.0; R[4] = 1.0; R[8] = 1.0;
    }
}

__device__ void solve_batch(double* ws, const double* acc, int b) {
    double A[6][6], rhs[6];
    int k = 0;
    for (int f = 0; f < 6; f++)
        for (int g = f; g < 6; g++) {
            A[f][g] = acc[k]; A[g][f] = acc[k]; k++;
        }
    for (int f = 0; f < 6; f++) rhs[f] = -acc[21 + f];

    double tr = A[0][0] + A[1][1] + A[2][2] + A[3][3] + A[4][4] + A[5][5];
    double damp = 1e-4 * tr / 6.0 + 1e-6;
    for (int f = 0; f < 6; f++) A[f][f] += damp;

    double L[6][6];
    for (int i = 0; i < 6; i++)
        for (int j = 0; j <= i; j++) {
            double sum = A[i][j];
            for (int m = 0; m < j; m++) sum -= L[i][m] * L[j][m];
            if (i == j) L[i][j] = sqrt(fmax(sum, 1e-30));
            else        L[i][j] = sum / L[j][j];
        }
    double y[6];
    for (int i = 0; i < 6; i++) {
        double s = rhs[i];
        for (int m = 0; m < i; m++) s -= L[i][m] * y[m];
        y[i] = s / L[i][i];
    }
    double dx[6];
    for (int i = 5; i >= 0; i--) {
        double s = y[i];
        for (int m = i + 1; m < 6; m++) s -= L[m][i] * dx[m];
        dx[i] = s / L[i][i];
    }

    double* t = ws + T_OFF + b * 3;
    t[0] += dx[0]; t[1] += dx[1]; t[2] += dx[2];

    double wx = dx[3], wy = dx[4], wz = dx[5];
    double th = sqrt(wx*wx + wy*wy + wz*wz);
    th = fmax(th, 1e-8);
    double kx = wx/th, ky = wy/th, kz = wz/th;
    double st = sin(th), ct = 1.0 - cos(th);
    double E[9];
    E[0] = 1.0 + ct*(kx*kx - 1.0);
    E[1] = -st*kz + ct*kx*ky;
    E[2] =  st*ky + ct*kx*kz;
    E[3] =  st*kz + ct*ky*kx;
    E[4] = 1.0 + ct*(ky*ky - 1.0);
    E[5] = -st*kx + ct*ky*kz;
    E[6] = -st*ky + ct*kz*kx;
    E[7] =  st*kx + ct*kz*ky;
    E[8] = 1.0 + ct*(kz*kz - 1.0);

    double* R = ws + R_OFF + b * 9;
    double Rn[9];
    for (int i = 0; i < 3; i++)
        for (int j = 0; j < 3; j++)
            Rn[i*3+j] = E[i*3+0]*R[0*3+j] + E[i*3+1]*R[1*3+j] + E[i*3+2]*R[2*3+j];
    for (int i = 0; i < 9; i++) R[i] = Rn[i];
}

__device__ void loss_16(const float* pose, const double* ws, float* out) {
    int lane = threadIdx.x;
    double rot = 0.0, trans = 0.0;
    if (lane < NB) {
        const float* P0 = pose;
        const float* Pb = pose + lane * 16;
        double R0t[9];
        for (int i = 0; i < 3; i++)
            for (int j = 0; j < 3; j++) R0t[i*3+j] = (double)P0[j*4+i];
        double t0i[3];
        for (int i = 0; i < 3; i++)
            t0i[i] = -(R0t[i*3+0]*P0[0*4+3] + R0t[i*3+1]*P0[1*4+3] + R0t[i*3+2]*P0[2*4+3]);
        double Rg[9], tg[3];
        for (int i = 0; i < 3; i++) {
            for (int j = 0; j < 3; j++)
                Rg[i*3+j] = R0t[i*3+0]*Pb[0*4+j] + R0t[i*3+1]*Pb[1*4+j] + R0t[i*3+2]*Pb[2*4+j];
            tg[i] = R0t[i*3+0]*Pb[0*4+3] + R0t[i*3+1]*Pb[1*4+3] + R0t[i*3+2]*Pb[2*4+3] + t0i[i];
        }
        const double* Q0  = ws + R_OFF;
        const double* q0t = ws + T_OFF;
        const double* Qb  = ws + R_OFF + lane * 9;
        const double* qbt = ws + T_OFF + lane * 3;
        double Rp0t[9];
        for (int i = 0; i < 3; i++)
            for (int j = 0; j < 3; j++) Rp0t[i*3+j] = Q0[j*3+i];
        double tp0i[3];
        for (int i = 0; i < 3; i++)
            tp0i[i] = -(Rp0t[i*3+0]*q0t[0] + Rp0t[i*3+1]*q0t[1] + Rp0t[i*3+2]*q0t[2]);
        double Rp[9], tp[3];
        for (int i = 0; i < 3; i++) {
            for (int j = 0; j < 3; j++)
                Rp[i*3+j] = Rp0t[i*3+0]*Qb[0*3+j] + Rp0t[i*3+1]*Qb[1*3+j] + Rp0t[i*3+2]*Qb[2*3+j];
            tp[i] = Rp0t[i*3+0]*qbt[0] + Rp0t[i*3+1]*qbt[1] + Rp0t[i*3+2]*qbt[2] + tp0i[i];
        }
        double trace = 0.0;
        for (int i = 0; i < 3; i++)
            trace += Rp[0*3+i]*Rg[0*3+i] + Rp[1*3+i]*Rg[1*3+i] + Rp[2*3+i]*Rg[2*3+i];
        double cosang = 0.5 * (trace - 1.0);
        double lo = -1.0 + 1e-7, hi = 1.0 - 1e-7;
        cosang = fmin(fmax(cosang, lo), hi);
        rot = acos(cosang);
        double d0 = tp[0]-tg[0], d1 = tp[1]-tg[1], d2 = tp[2]-tg[2];
        trans = sqrt(d0*d0 + d1*d1 + d2*d2);
    }
    if (lane < 64) {
        for (int off = 8; off > 0; off >>= 1) {
            rot   += __shfl_down(rot, off, 64);
            trans += __shfl_down(trans, off, 64);
        }
        if (lane == 0) {
            rot /= NB; trans /= NB;
            out[0] = (float)(rot + trans);
            out[1] = (float)rot;
            out[2] = (float)trans;
        }
    }
}

__global__ __launch_bounds__(TPB) void reduce_k(const float* __restrict__ x3d,
                                                const float* __restrict__ conf,
                                                const float* __restrict__ Kmat,
                                                const float* __restrict__ pose,
                                                float* __restrict__ out,
                                                double* ws, int it, int last) {
    // batch = blockIdx % 16 so all blocks of a batch share an XCD (round-robin map)
    const int b = blockIdx.x % NB;
    const int chunk = blockIdx.x / NB;

    const double* Rd = ws + R_OFF + b * 9;
    const double* td = ws + T_OFF + b * 3;
    float R[9], t[3];
    #pragma unroll
    for (int i = 0; i < 9; i++) R[i] = (float)Rd[i];
    #pragma unroll
    for (int i = 0; i < 3; i++) t[i] = (float)td[i];

    const float fx = Kmat[b*9 + 0];
    const float fy = Kmat[b*9 + 4];
    const float cx = Kmat[b*9 + 2];
    const float cy = Kmat[b*9 + 5];
    const float delta = (float)(0.1 * sqrt(((double)(IMW*IMW - 1) + (double)(IMH*IMH - 1)) / 12.0));

    const float* P  = x3d  + (size_t)b * NPIX * 3;
    const float* Wp = conf + (size_t)b * NPIX;

    float facc[27];
    #pragma unroll
    for (int i = 0; i < 27; i++) facc[i] = 0.0f;

    for (int n = chunk * TPB + threadIdx.x; n < NPIX; n += BPB * TPB) {
        float px = P[3*n + 0];
        float py = P[3*n + 1];
        float pz = P[3*n + 2];
        float w  = Wp[n];

        float Xx = R[0]*px + R[1]*py + R[2]*pz + t[0];
        float Xy = R[3]*px + R[4]*py + R[5]*pz + t[1];
        float Xz = R[6]*px + R[7]*py + R[8]*pz + t[2];
        float z  = fmaxf(Xz, 0.01f);
        float iz = 1.0f / z;

        int v0 = n / IMW;
        int u0 = n - v0 * IMW;
        float rx = fx * Xx * iz + (cx - (float)u0);
        float ry = fy * Xy * iz + (cy - (float)v0);

        float wrx = w * rx, wry = w * ry;
        float rn = sqrtf(wrx*wrx + wry*wry);
        float rob2 = fminf(1.0f, delta / fmaxf(rn, 1e-8f));
        float sq = w * sqrtf(rob2);          // sqrt(s): fold robust weight into J

        // scaled Jacobian entries
        float a  = sq * fx * iz;
        float bb = -sq * fx * Xx * iz * iz;
        float c  = sq * fy * iz;
        float d  = -sq * fy * Xy * iz * iz;

        float j0[6] = { a, 0.0f, bb,  bb*Xy,          a*Xz - bb*Xx, -a*Xy };
        float j1[6] = { 0.0f, c,  d, -c*Xz + d*Xy,   -d*Xx,          c*Xx };
        float rxs = sq * rx, rys = sq * ry;

        int k = 0;
        #pragma unroll
        for (int f = 0; f < 6; ++f) {
            #pragma unroll
            for (int g = f; g < 6; ++g) {
                facc[k] += j0[f]*j0[g] + j1[f]*j1[g];   // 2 fmac each (zeros folded)
                k++;
            }
        }
        #pragma unroll
        for (int f = 0; f < 6; ++f)
            facc[21 + f] += j0[f]*rxs + j1[f]*rys;
    }

    // f32 wave reduce (pairwise), f64 from wave partials on
    int lane = threadIdx.x & 63;
    int wave = threadIdx.x >> 6;
    __shared__ double lds[TPB / 64][27];
    #pragma unroll
    for (int i = 0; i < 27; i++) {
        float v = facc[i];
        for (int off = 32; off > 0; off >>= 1) v += __shfl_down(v, off, 64);
        if (lane == 0) lds[wave][i] = (double)v;
    }
    __syncthreads();

    double* acc = ws + ACC_OFF + ((size_t)it * NB + b) * 27;
    if (threadIdx.x < 27) {
        double v = 0.0;
        #pragma unroll
        for (int wv = 0; wv < TPB/64; wv++) v += lds[wv][threadIdx.x];
        atomicAdd(acc + threadIdx.x, v);
    }
    __threadfence();
    __syncthreads();

    __shared__ int s_solver, s_loss;
    int* cnt = (int*)(ws + WS_DOUBLES);
    if (threadIdx.x == 0) {
        s_loss = 0;
        int old = atomicAdd(&cnt[it * NB + b], 1);
        s_solver = (old == BPB - 1) ? 1 : 0;
    }
    __syncthreads();
    if (s_solver) {
        if (threadIdx.x == 0) {
            __threadfence();               // acquire all blocks' acc adds
            solve_batch(ws, acc, b);
            __threadfence();               // release pose update
            if (last) {
                int o2 = atomicAdd(&cnt[NITER * NB], 1);
                if (o2 == NB - 1) s_loss = 1;
            }
        }
        __syncthreads();
        if (s_loss) {
            __threadfence();               // acquire all batches' pose updates
            loss_16(pose, ws, out);
        }
    }
}

extern "C" void kernel_launch(void* const* d_in, const int* in_sizes, int n_in,
                              void* d_out, int out_size, void* d_ws, size_t ws_size,
                              hipStream_t stream) {
    const float* x3d  = (const float*)d_in[0];
    const float* conf = (const float*)d_in[1];
    const float* Kmat = (const float*)d_in[2];
    const float* pose = (const float*)d_in[3];
    float* out = (float*)d_out;
    double* ws = (double*)d_ws;

    hipLaunchKernelGGL(init_k, dim3(1), dim3(TPB), 0, stream, ws);
    for (int it = 0; it < NITER; ++it) {
        hipLaunchKernelGGL(reduce_k, dim3(NBLK), dim3(TPB), 0, stream,
                           x3d, conf, Kmat, pose, out, ws, it, (it == NITER - 1) ? 1 : 0);
    }
}

// Round 4
// 193.888 us; speedup vs baseline: 3.0162x; 1.9424x over previous
//
#include <hip/hip_runtime.h>
#include <math.h>

#define NB 16
#define IMH 288
#define IMW 384
#define NPIX (IMH*IMW)
#define BPB 108           // blocks per batch: 108*256*4 = 110592 = NPIX exactly
#define NBLK (NB*BPB)     // 1728
#define TPB 256
#define NITER 5

// ws layout (doubles): R[16][9] | t[16][3] | acc[NITER][16][27] ; then ints cnt[NITER*16+1]
#define R_OFF 0
#define T_OFF (NB*9)
#define ACC_OFF (NB*12)
#define WS_DOUBLES (NB*12 + NITER*NB*27)

__global__ void init_k(double* ws) {
    int i = threadIdx.x;
    for (int k = i; k < WS_DOUBLES; k += TPB) ws[k] = 0.0;
    int* cnt = (int*)(ws + WS_DOUBLES);
    for (int k = i; k < NITER * NB + 1; k += TPB) cnt[k] = 0;
    __syncthreads();
    if (i < NB) {
        double* R = ws + R_OFF + i * 9;
        R[0] = 1.0; R[4] = 1.0; R[8] = 1.0;
    }
}

__device__ void solve_batch(double* ws, const double* acc, int b) {
    double A[6][6], rhs[6];
    int k = 0;
    for (int f = 0; f < 6; f++)
        for (int g = f; g < 6; g++) {
            A[f][g] = acc[k]; A[g][f] = acc[k]; k++;
        }
    for (int f = 0; f < 6; f++) rhs[f] = -acc[21 + f];

    double tr = A[0][0] + A[1][1] + A[2][2] + A[3][3] + A[4][4] + A[5][5];
    double damp = 1e-4 * tr / 6.0 + 1e-6;
    for (int f = 0; f < 6; f++) A[f][f] += damp;

    double L[6][6];
    for (int i = 0; i < 6; i++)
        for (int j = 0; j <= i; j++) {
            double sum = A[i][j];
            for (int m = 0; m < j; m++) sum -= L[i][m] * L[j][m];
            if (i == j) L[i][j] = sqrt(fmax(sum, 1e-30));
            else        L[i][j] = sum / L[j][j];
        }
    double y[6];
    for (int i = 0; i < 6; i++) {
        double s = rhs[i];
        for (int m = 0; m < i; m++) s -= L[i][m] * y[m];
        y[i] = s / L[i][i];
    }
    double dx[6];
    for (int i = 5; i >= 0; i--) {
        double s = y[i];
        for (int m = i + 1; m < 6; m++) s -= L[m][i] * dx[m];
        dx[i] = s / L[i][i];
    }

    double* t = ws + T_OFF + b * 3;
    t[0] += dx[0]; t[1] += dx[1]; t[2] += dx[2];

    double wx = dx[3], wy = dx[4], wz = dx[5];
    double th = sqrt(wx*wx + wy*wy + wz*wz);
    th = fmax(th, 1e-8);
    double kx = wx/th, ky = wy/th, kz = wz/th;
    double st = sin(th), ct = 1.0 - cos(th);
    double E[9];
    E[0] = 1.0 + ct*(kx*kx - 1.0);
    E[1] = -st*kz + ct*kx*ky;
    E[2] =  st*ky + ct*kx*kz;
    E[3] =  st*kz + ct*ky*kx;
    E[4] = 1.0 + ct*(ky*ky - 1.0);
    E[5] = -st*kx + ct*ky*kz;
    E[6] = -st*ky + ct*kz*kx;
    E[7] =  st*kx + ct*kz*ky;
    E[8] = 1.0 + ct*(kz*kz - 1.0);

    double* R = ws + R_OFF + b * 9;
    double Rn[9];
    for (int i = 0; i < 3; i++)
        for (int j = 0; j < 3; j++)
            Rn[i*3+j] = E[i*3+0]*R[0*3+j] + E[i*3+1]*R[1*3+j] + E[i*3+2]*R[2*3+j];
    for (int i = 0; i < 9; i++) R[i] = Rn[i];
}

__device__ void loss_16(const float* pose, const double* ws, float* out) {
    int lane = threadIdx.x;
    double rot = 0.0, trans = 0.0;
    if (lane < NB) {
        const float* P0 = pose;
        const float* Pb = pose + lane * 16;
        double R0t[9];
        for (int i = 0; i < 3; i++)
            for (int j = 0; j < 3; j++) R0t[i*3+j] = (double)P0[j*4+i];
        double t0i[3];
        for (int i = 0; i < 3; i++)
            t0i[i] = -(R0t[i*3+0]*P0[0*4+3] + R0t[i*3+1]*P0[1*4+3] + R0t[i*3+2]*P0[2*4+3]);
        double Rg[9], tg[3];
        for (int i = 0; i < 3; i++) {
            for (int j = 0; j < 3; j++)
                Rg[i*3+j] = R0t[i*3+0]*Pb[0*4+j] + R0t[i*3+1]*Pb[1*4+j] + R0t[i*3+2]*Pb[2*4+j];
            tg[i] = R0t[i*3+0]*Pb[0*4+3] + R0t[i*3+1]*Pb[1*4+3] + R0t[i*3+2]*Pb[2*4+3] + t0i[i];
        }
        const double* Q0  = ws + R_OFF;
        const double* q0t = ws + T_OFF;
        const double* Qb  = ws + R_OFF + lane * 9;
        const double* qbt = ws + T_OFF + lane * 3;
        double Rp0t[9];
        for (int i = 0; i < 3; i++)
            for (int j = 0; j < 3; j++) Rp0t[i*3+j] = Q0[j*3+i];
        double tp0i[3];
        for (int i = 0; i < 3; i++)
            tp0i[i] = -(Rp0t[i*3+0]*q0t[0] + Rp0t[i*3+1]*q0t[1] + Rp0t[i*3+2]*q0t[2]);
        double Rp[9], tp[3];
        for (int i = 0; i < 3; i++) {
            for (int j = 0; j < 3; j++)
                Rp[i*3+j] = Rp0t[i*3+0]*Qb[0*3+j] + Rp0t[i*3+1]*Qb[1*3+j] + Rp0t[i*3+2]*Qb[2*3+j];
            tp[i] = Rp0t[i*3+0]*qbt[0] + Rp0t[i*3+1]*qbt[1] + Rp0t[i*3+2]*qbt[2] + tp0i[i];
        }
        double trace = 0.0;
        for (int i = 0; i < 3; i++)
            trace += Rp[0*3+i]*Rg[0*3+i] + Rp[1*3+i]*Rg[1*3+i] + Rp[2*3+i]*Rg[2*3+i];
        double cosang = 0.5 * (trace - 1.0);
        double lo = -1.0 + 1e-7, hi = 1.0 - 1e-7;
        cosang = fmin(fmax(cosang, lo), hi);
        rot = acos(cosang);
        double d0 = tp[0]-tg[0], d1 = tp[1]-tg[1], d2 = tp[2]-tg[2];
        trans = sqrt(d0*d0 + d1*d1 + d2*d2);
    }
    if (lane < 64) {
        for (int off = 8; off > 0; off >>= 1) {
            rot   += __shfl_down(rot, off, 64);
            trans += __shfl_down(trans, off, 64);
        }
        if (lane == 0) {
            rot /= NB; trans /= NB;
            out[0] = (float)(rot + trans);
            out[1] = (float)rot;
            out[2] = (float)trans;
        }
    }
}

__global__ __launch_bounds__(TPB) void reduce_k(const float* __restrict__ x3d,
                                                const float* __restrict__ conf,
                                                const float* __restrict__ Kmat,
                                                const float* __restrict__ pose,
                                                float* __restrict__ out,
                                                double* ws, int it, int last) {
    const int b = blockIdx.x % NB;        // all blocks of batch b -> XCD b%8
    const int chunk = blockIdx.x / NB;

    const double* Rd = ws + R_OFF + b * 9;
    const double* td = ws + T_OFF + b * 3;
    float R[9], t[3];
    #pragma unroll
    for (int i = 0; i < 9; i++) R[i] = (float)Rd[i];
    #pragma unroll
    for (int i = 0; i < 3; i++) t[i] = (float)td[i];

    const float fx = Kmat[b*9 + 0];
    const float fy = Kmat[b*9 + 4];
    const float cx = Kmat[b*9 + 2];
    const float cy = Kmat[b*9 + 5];
    const float delta = (float)(0.1 * sqrt(((double)(IMW*IMW - 1) + (double)(IMH*IMH - 1)) / 12.0));

    float facc[27];
    #pragma unroll
    for (int i = 0; i < 27; i++) facc[i] = 0.0f;

    // 4 points per thread, single trip, vectorized loads
    const int ft = chunk * TPB + threadIdx.x;           // [0, 27648)
    const float4* P4 = reinterpret_cast<const float4*>(x3d + (size_t)b * NPIX * 3) + (size_t)ft * 3;
    const float4 va = P4[0];
    const float4 vb = P4[1];
    const float4 vc = P4[2];
    const float4 vw = reinterpret_cast<const float4*>(conf + (size_t)b * NPIX)[ft];
    const int n0 = ft * 4;

    float ppx[4] = { va.x, va.w, vb.z, vc.y };
    float ppy[4] = { va.y, vb.x, vb.w, vc.z };
    float ppz[4] = { va.z, vb.y, vc.x, vc.w };
    float pw[4]  = { vw.x, vw.y, vw.z, vw.w };

    #pragma unroll
    for (int g = 0; g < 4; ++g) {
        float px = ppx[g], py = ppy[g], pz = ppz[g], w = pw[g];
        int n = n0 + g;

        float Xx = R[0]*px + R[1]*py + R[2]*pz + t[0];
        float Xy = R[3]*px + R[4]*py + R[5]*pz + t[1];
        float Xz = R[6]*px + R[7]*py + R[8]*pz + t[2];
        float z  = fmaxf(Xz, 0.01f);
        float iz = 1.0f / z;

        int v0 = n / IMW;
        int u0 = n - v0 * IMW;
        float rx = fx * Xx * iz + (cx - (float)u0);
        float ry = fy * Xy * iz + (cy - (float)v0);

        float wrx = w * rx, wry = w * ry;
        float rn = sqrtf(wrx*wrx + wry*wry);
        float rob2 = fminf(1.0f, delta / fmaxf(rn, 1e-8f));
        float sq = w * sqrtf(rob2);          // sqrt(robust weight) folded into J

        float a  = sq * fx * iz;
        float bb = -sq * fx * Xx * iz * iz;
        float c  = sq * fy * iz;
        float d  = -sq * fy * Xy * iz * iz;

        float j0[6] = { a, 0.0f, bb,  bb*Xy,          a*Xz - bb*Xx, -a*Xy };
        float j1[6] = { 0.0f, c,  d, -c*Xz + d*Xy,   -d*Xx,          c*Xx };
        float rxs = sq * rx, rys = sq * ry;

        int k = 0;
        #pragma unroll
        for (int f = 0; f < 6; ++f) {
            #pragma unroll
            for (int gg = f; gg < 6; ++gg) {
                facc[k] += j0[f]*j0[gg] + j1[f]*j1[gg];
                k++;
            }
        }
        #pragma unroll
        for (int f = 0; f < 6; ++f)
            facc[21 + f] += j0[f]*rxs + j1[f]*rys;
    }

    // f32 wave reduce, f64 from wave partials on
    int lane = threadIdx.x & 63;
    int wave = threadIdx.x >> 6;
    __shared__ double lds[TPB / 64][27];
    #pragma unroll
    for (int i = 0; i < 27; i++) {
        float v = facc[i];
        for (int off = 32; off > 0; off >>= 1) v += __shfl_down(v, off, 64);
        if (lane == 0) lds[wave][i] = (double)v;
    }
    __syncthreads();

    double* acc = ws + ACC_OFF + ((size_t)it * NB + b) * 27;
    if (threadIdx.x < 27) {
        double v = 0.0;
        #pragma unroll
        for (int wv = 0; wv < TPB/64; wv++) v += lds[wv][threadIdx.x];
        atomicAdd(acc + threadIdx.x, v);
    }
    // __syncthreads() drains vmcnt -> the 27 device-scope atomics are globally
    // performed before thread 0 bumps the arrival counter. No all-thread fence.
    __syncthreads();

    __shared__ int s_solver, s_loss;
    int* cnt = (int*)(ws + WS_DOUBLES);
    if (threadIdx.x == 0) {
        s_loss = 0;
        int old = atomicAdd(&cnt[it * NB + b], 1);
        s_solver = (old == BPB - 1) ? 1 : 0;
    }
    __syncthreads();
    if (s_solver) {
        if (threadIdx.x == 0) {
            __threadfence();               // acquire: invalidate stale cached acc
            solve_batch(ws, acc, b);
            __threadfence();               // release: push pose to coherent point
            if (last) {
                int o2 = atomicAdd(&cnt[NITER * NB], 1);
                if (o2 == NB - 1) s_loss = 1;
            }
        }
        __syncthreads();
        if (s_loss) {
            __threadfence();               // acquire: see all batches' poses
            loss_16(pose, ws, out);
        }
    }
}

extern "C" void kernel_launch(void* const* d_in, const int* in_sizes, int n_in,
                              void* d_out, int out_size, void* d_ws, size_t ws_size,
                              hipStream_t stream) {
    const float* x3d  = (const float*)d_in[0];
    const float* conf = (const float*)d_in[1];
    const float* Kmat = (const float*)d_in[2];
    const float* pose = (const float*)d_in[3];
    float* out = (float*)d_out;
    double* ws = (double*)d_ws;

    hipLaunchKernelGGL(init_k, dim3(1), dim3(TPB), 0, stream, ws);
    for (int it = 0; it < NITER; ++it) {
        hipLaunchKernelGGL(reduce_k, dim3(NBLK), dim3(TPB), 0, stream,
                           x3d, conf, Kmat, pose, out, ws, it, (it == NITER - 1) ? 1 : 0);
    }
}

// Round 5
// 126.847 us; speedup vs baseline: 4.6104x; 1.5285x over previous
//
#include <hip/hip_runtime.h>
#include <math.h>

#define NB 16
#define IMH 288
#define IMW 384
#define NPIX (IMH*IMW)
#define BPB 108           // blocks per batch: 108*256*4 = 110592 = NPIX exactly
#define NBLK (NB*BPB)     // 1728
#define TPB 256
#define NITER 5

// ws layout (doubles): R[16][9] | t[16][3] | acc[NITER][16][27]
#define R_OFF 0
#define T_OFF (NB*9)
#define ACC_OFF (NB*12)
#define WS_DOUBLES (NB*12 + NITER*NB*27)

__global__ void init_k(double* ws) {
    int i = threadIdx.x;
    for (int k = i; k < WS_DOUBLES; k += TPB) ws[k] = 0.0;
    __syncthreads();
    if (i < NB) {
        double* R = ws + R_OFF + i * 9;
        R[0] = 1.0; R[4] = 1.0; R[8] = 1.0;
    }
}

__global__ __launch_bounds__(TPB) void reduce_k(const float* __restrict__ x3d,
                                                const float* __restrict__ conf,
                                                const float* __restrict__ Kmat,
                                                double* __restrict__ ws, int it) {
    const int b = blockIdx.x / BPB;       // contiguous blocks per batch
    const int chunk = blockIdx.x % BPB;

    const double* Rd = ws + R_OFF + b * 9;
    const double* td = ws + T_OFF + b * 3;
    float R[9], t[3];
    #pragma unroll
    for (int i = 0; i < 9; i++) R[i] = (float)Rd[i];
    #pragma unroll
    for (int i = 0; i < 3; i++) t[i] = (float)td[i];

    const float fx = Kmat[b*9 + 0];
    const float fy = Kmat[b*9 + 4];
    const float cx = Kmat[b*9 + 2];
    const float cy = Kmat[b*9 + 5];
    const float delta = (float)(0.1 * sqrt(((double)(IMW*IMW - 1) + (double)(IMH*IMH - 1)) / 12.0));

    float facc[27];
    #pragma unroll
    for (int i = 0; i < 27; i++) facc[i] = 0.0f;

    // 4 points per thread, single trip, vectorized loads
    const int ft = chunk * TPB + threadIdx.x;           // [0, 27648)
    const float4* P4 = reinterpret_cast<const float4*>(x3d + (size_t)b * NPIX * 3) + (size_t)ft * 3;
    const float4 va = P4[0];
    const float4 vb = P4[1];
    const float4 vc = P4[2];
    const float4 vw = reinterpret_cast<const float4*>(conf + (size_t)b * NPIX)[ft];
    const int n0 = ft * 4;

    float ppx[4] = { va.x, va.w, vb.z, vc.y };
    float ppy[4] = { va.y, vb.x, vb.w, vc.z };
    float ppz[4] = { va.z, vb.y, vc.x, vc.w };
    float pw[4]  = { vw.x, vw.y, vw.z, vw.w };

    #pragma unroll
    for (int g = 0; g < 4; ++g) {
        float px = ppx[g], py = ppy[g], pz = ppz[g], w = pw[g];
        int n = n0 + g;

        float Xx = R[0]*px + R[1]*py + R[2]*pz + t[0];
        float Xy = R[3]*px + R[4]*py + R[5]*pz + t[1];
        float Xz = R[6]*px + R[7]*py + R[8]*pz + t[2];
        float z  = fmaxf(Xz, 0.01f);
        float iz = 1.0f / z;

        int v0 = n / IMW;
        int u0 = n - v0 * IMW;
        float rx = fx * Xx * iz + (cx - (float)u0);
        float ry = fy * Xy * iz + (cy - (float)v0);

        float wrx = w * rx, wry = w * ry;
        float rn = sqrtf(wrx*wrx + wry*wry);
        float rob2 = fminf(1.0f, delta / fmaxf(rn, 1e-8f));
        float sq = w * sqrtf(rob2);          // sqrt(robust weight) folded into J

        float a  = sq * fx * iz;
        float bb = -sq * fx * Xx * iz * iz;
        float c  = sq * fy * iz;
        float d  = -sq * fy * Xy * iz * iz;

        float j0[6] = { a, 0.0f, bb,  bb*Xy,          a*Xz - bb*Xx, -a*Xy };
        float j1[6] = { 0.0f, c,  d, -c*Xz + d*Xy,   -d*Xx,          c*Xx };
        float rxs = sq * rx, rys = sq * ry;

        int k = 0;
        #pragma unroll
        for (int f = 0; f < 6; ++f) {
            #pragma unroll
            for (int gg = f; gg < 6; ++gg) {
                facc[k] += j0[f]*j0[gg] + j1[f]*j1[gg];
                k++;
            }
        }
        #pragma unroll
        for (int f = 0; f < 6; ++f)
            facc[21 + f] += j0[f]*rxs + j1[f]*rys;
    }

    // f32 wave reduce (pairwise), f64 from wave partials on
    int lane = threadIdx.x & 63;
    int wave = threadIdx.x >> 6;
    __shared__ double lds[TPB / 64][27];
    #pragma unroll
    for (int i = 0; i < 27; i++) {
        float v = facc[i];
        for (int off = 32; off > 0; off >>= 1) v += __shfl_down(v, off, 64);
        if (lane == 0) lds[wave][i] = (double)v;
    }
    __syncthreads();

    double* acc = ws + ACC_OFF + ((size_t)it * NB + b) * 27;
    if (threadIdx.x < 27) {
        double v = 0.0;
        #pragma unroll
        for (int wv = 0; wv < TPB/64; wv++) v += lds[wv][threadIdx.x];
        atomicAdd(acc + threadIdx.x, v);
    }
}

// One wave; lanes 0..15 each solve one batch. Fully unrolled -> registers only.
__global__ __launch_bounds__(64) void solve_k(double* __restrict__ ws,
                                              const float* __restrict__ pose,
                                              float* __restrict__ out,
                                              int it, int last) {
    const int b = threadIdx.x;
    if (b < NB) {
        const double* acc = ws + ACC_OFF + ((size_t)it * NB + b) * 27;

        double A[6][6], rhs[6], inv[6];
        {
            int k = 0;
            #pragma unroll
            for (int f = 0; f < 6; f++) {
                #pragma unroll 6
                for (int g = f; g < 6; g++) {
                    double v = acc[k];
                    A[f][g] = v; A[g][f] = v; k++;
                }
            }
        }
        #pragma unroll
        for (int f = 0; f < 6; f++) rhs[f] = -acc[21 + f];

        double tr = A[0][0] + A[1][1] + A[2][2] + A[3][3] + A[4][4] + A[5][5];
        double damp = 1e-4 * tr / 6.0 + 1e-6;
        #pragma unroll
        for (int f = 0; f < 6; f++) A[f][f] += damp;

        // In-place Cholesky on lower triangle, reciprocal per column
        #pragma unroll
        for (int j = 0; j < 6; j++) {
            double s = A[j][j];
            #pragma unroll 6
            for (int m = 0; m < j; m++) s -= A[j][m] * A[j][m];
            double d = sqrt(fmax(s, 1e-30));
            A[j][j] = d;
            inv[j] = 1.0 / d;
            #pragma unroll 6
            for (int i = j + 1; i < 6; i++) {
                double s2 = A[i][j];
                #pragma unroll 6
                for (int m = 0; m < j; m++) s2 -= A[i][m] * A[j][m];
                A[i][j] = s2 * inv[j];
            }
        }
        // forward substitution (rhs -> y in place)
        #pragma unroll
        for (int i = 0; i < 6; i++) {
            double s = rhs[i];
            #pragma unroll 6
            for (int m = 0; m < i; m++) s -= A[i][m] * rhs[m];
            rhs[i] = s * inv[i];
        }
        // back substitution (rhs -> dx in place)
        #pragma unroll
        for (int i = 5; i >= 0; i--) {
            double s = rhs[i];
            #pragma unroll 6
            for (int m = i + 1; m < 6; m++) s -= A[m][i] * rhs[m];
            rhs[i] = s * inv[i];
        }

        double* t = ws + T_OFF + b * 3;
        t[0] += rhs[0]; t[1] += rhs[1]; t[2] += rhs[2];

        double wx = rhs[3], wy = rhs[4], wz = rhs[5];
        double th = sqrt(wx*wx + wy*wy + wz*wz);
        th = fmax(th, 1e-8);
        double ith = 1.0 / th;
        double kx = wx*ith, ky = wy*ith, kz = wz*ith;
        float stf, ctf;
        sincosf((float)th, &stf, &ctf);        // f32 trig == reference semantics
        double st = (double)stf, ct = 1.0 - (double)ctf;
        double E[9];
        E[0] = 1.0 + ct*(kx*kx - 1.0);
        E[1] = -st*kz + ct*kx*ky;
        E[2] =  st*ky + ct*kx*kz;
        E[3] =  st*kz + ct*ky*kx;
        E[4] = 1.0 + ct*(ky*ky - 1.0);
        E[5] = -st*kx + ct*ky*kz;
        E[6] = -st*ky + ct*kz*kx;
        E[7] =  st*kx + ct*kz*ky;
        E[8] = 1.0 + ct*(kz*kz - 1.0);

        double* R = ws + R_OFF + b * 9;
        double R0 = R[0], R1 = R[1], R2 = R[2];
        double R3 = R[3], R4 = R[4], R5 = R[5];
        double R6 = R[6], R7 = R[7], R8 = R[8];
        R[0] = E[0]*R0 + E[1]*R3 + E[2]*R6;
        R[1] = E[0]*R1 + E[1]*R4 + E[2]*R7;
        R[2] = E[0]*R2 + E[1]*R5 + E[2]*R8;
        R[3] = E[3]*R0 + E[4]*R3 + E[5]*R6;
        R[4] = E[3]*R1 + E[4]*R4 + E[5]*R7;
        R[5] = E[3]*R2 + E[4]*R5 + E[5]*R8;
        R[6] = E[6]*R0 + E[7]*R3 + E[8]*R6;
        R[7] = E[6]*R1 + E[7]*R4 + E[8]*R7;
        R[8] = E[6]*R2 + E[7]*R5 + E[8]*R8;
    }

    if (last) {
        __syncthreads();
        int lane = threadIdx.x;
        double rot = 0.0, trans = 0.0;
        if (lane < NB) {
            const float* P0 = pose;
            const float* Pb = pose + lane * 16;
            double R0t[9];
            #pragma unroll
            for (int i = 0; i < 3; i++)
                #pragma unroll
                for (int j = 0; j < 3; j++) R0t[i*3+j] = (double)P0[j*4+i];
            double t0i[3];
            #pragma unroll
            for (int i = 0; i < 3; i++)
                t0i[i] = -(R0t[i*3+0]*P0[0*4+3] + R0t[i*3+1]*P0[1*4+3] + R0t[i*3+2]*P0[2*4+3]);
            double Rg[9], tg[3];
            #pragma unroll
            for (int i = 0; i < 3; i++) {
                #pragma unroll
                for (int j = 0; j < 3; j++)
                    Rg[i*3+j] = R0t[i*3+0]*Pb[0*4+j] + R0t[i*3+1]*Pb[1*4+j] + R0t[i*3+2]*Pb[2*4+j];
                tg[i] = R0t[i*3+0]*Pb[0*4+3] + R0t[i*3+1]*Pb[1*4+3] + R0t[i*3+2]*Pb[2*4+3] + t0i[i];
            }
            const double* Q0  = ws + R_OFF;
            const double* q0t = ws + T_OFF;
            const double* Qb  = ws + R_OFF + lane * 9;
            const double* qbt = ws + T_OFF + lane * 3;
            double Rp0t[9];
            #pragma unroll
            for (int i = 0; i < 3; i++)
                #pragma unroll
                for (int j = 0; j < 3; j++) Rp0t[i*3+j] = Q0[j*3+i];
            double tp0i[3];
            #pragma unroll
            for (int i = 0; i < 3; i++)
                tp0i[i] = -(Rp0t[i*3+0]*q0t[0] + Rp0t[i*3+1]*q0t[1] + Rp0t[i*3+2]*q0t[2]);
            double Rp[9], tp[3];
            #pragma unroll
            for (int i = 0; i < 3; i++) {
                #pragma unroll
                for (int j = 0; j < 3; j++)
                    Rp[i*3+j] = Rp0t[i*3+0]*Qb[0*3+j] + Rp0t[i*3+1]*Qb[1*3+j] + Rp0t[i*3+2]*Qb[2*3+j];
                tp[i] = Rp0t[i*3+0]*qbt[0] + Rp0t[i*3+1]*qbt[1] + Rp0t[i*3+2]*qbt[2] + tp0i[i];
            }
            double trace = 0.0;
            #pragma unroll
            for (int i = 0; i < 3; i++)
                trace += Rp[0*3+i]*Rg[0*3+i] + Rp[1*3+i]*Rg[1*3+i] + Rp[2*3+i]*Rg[2*3+i];
            double cosang = 0.5 * (trace - 1.0);
            double lo = -1.0 + 1e-7, hi = 1.0 - 1e-7;
            cosang = fmin(fmax(cosang, lo), hi);
            rot = acos(cosang);
            double d0 = tp[0]-tg[0], d1 = tp[1]-tg[1], d2 = tp[2]-tg[2];
            trans = sqrt(d0*d0 + d1*d1 + d2*d2);
        }
        for (int off = 8; off > 0; off >>= 1) {
            rot   += __shfl_down(rot, off, 64);
            trans += __shfl_down(trans, off, 64);
        }
        if (lane == 0) {
            rot /= NB; trans /= NB;
            out[0] = (float)(rot + trans);
            out[1] = (float)rot;
            out[2] = (float)trans;
        }
    }
}

extern "C" void kernel_launch(void* const* d_in, const int* in_sizes, int n_in,
                              void* d_out, int out_size, void* d_ws, size_t ws_size,
                              hipStream_t stream) {
    const float* x3d  = (const float*)d_in[0];
    const float* conf = (const float*)d_in[1];
    const float* Kmat = (const float*)d_in[2];
    const float* pose = (const float*)d_in[3];
    float* out = (float*)d_out;
    double* ws = (double*)d_ws;

    hipLaunchKernelGGL(init_k, dim3(1), dim3(TPB), 0, stream, ws);
    for (int it = 0; it < NITER; ++it) {
        hipLaunchKernelGGL(reduce_k, dim3(NBLK), dim3(TPB), 0, stream,
                           x3d, conf, Kmat, ws, it);
        hipLaunchKernelGGL(solve_k, dim3(1), dim3(64), 0, stream,
                           ws, pose, out, it, (it == NITER - 1) ? 1 : 0);
    }
}